// Round 1
// baseline (329.370 us; speedup 1.0000x reference)
//
#include <hip/hip_runtime.h>

// EmbeddingBag(mean): V=1e6, D=64, B=16384, L=50.
// One wave (64 lanes) per bag. A row is 64 fp32 = 256 B = 16 lanes * float4.
// Wave splits into 4 sub-groups of 16 lanes; sub-group s handles indices
// j = s, s+4, s+8, ... of the bag, accumulating float4 per lane. Then a
// 2-step __shfl_xor (^16, ^32) reduces across sub-groups; lanes 0..15 write
// the bag's 64 floats as one float4 each.

__global__ __launch_bounds__(256) void FreqAwareEmbedding_kernel(
    const int* __restrict__ indices,   // [T]
    const int* __restrict__ offsets,   // [B]
    const float4* __restrict__ weight4, // [V*16]  (V x 64 fp32 viewed as float4)
    float4* __restrict__ out4,          // [B*16]
    int B, int T)
{
    const int wave = (int)((blockIdx.x * blockDim.x + threadIdx.x) >> 6);
    if (wave >= B) return;
    const int lane = threadIdx.x & 63;
    const int sub  = lane >> 4;   // 0..3: which index-slot within the group of 4
    const int col  = lane & 15;   // float4 column within the 64-float row

    const int start = offsets[wave];
    const int end   = (wave + 1 < B) ? offsets[wave + 1] : T;
    const int count = end - start;

    float4 acc = make_float4(0.f, 0.f, 0.f, 0.f);

    for (int j = sub; j < count; j += 4) {
        const int idx = indices[start + j];
        const float4 v = weight4[(long long)idx * 16 + col];
        acc.x += v.x; acc.y += v.y; acc.z += v.z; acc.w += v.w;
    }

    // Reduce the 4 sub-group partials: lanes l, l^16, l^32, l^48 share `col`.
    #pragma unroll
    for (int m = 16; m <= 32; m <<= 1) {
        acc.x += __shfl_xor(acc.x, m, 64);
        acc.y += __shfl_xor(acc.y, m, 64);
        acc.z += __shfl_xor(acc.z, m, 64);
        acc.w += __shfl_xor(acc.w, m, 64);
    }

    const float inv = 1.0f / (float)((count > 0) ? count : 1);
    acc.x *= inv; acc.y *= inv; acc.z *= inv; acc.w *= inv;

    if (sub == 0) {
        out4[(long long)wave * 16 + col] = acc;
    }
}

extern "C" void kernel_launch(void* const* d_in, const int* in_sizes, int n_in,
                              void* d_out, int out_size, void* d_ws, size_t ws_size,
                              hipStream_t stream) {
    const int*   indices = (const int*)d_in[0];     // int64 in ref -> int32 on device
    const int*   offsets = (const int*)d_in[1];
    const float* weight  = (const float*)d_in[2];
    float*       out     = (float*)d_out;

    const int T = in_sizes[0];
    const int B = in_sizes[1];

    const int bags_per_block = 4;                   // 256 threads = 4 waves
    const int grid = (B + bags_per_block - 1) / bags_per_block;

    FreqAwareEmbedding_kernel<<<grid, 256, 0, stream>>>(
        indices, offsets, (const float4*)weight, (float4*)out, B, T);
}

// Round 3
// 325.792 us; speedup vs baseline: 1.0110x; 1.0110x over previous
//
#include <hip/hip_runtime.h>

// EmbeddingBag(mean): V=1e6, D=64, B=16384, L=50.
// One wave per bag; lanes = 4 sub-groups x 16 cols (float4 per lane = 256B row).
// Structure: ONE coalesced load puts the bag's <=64 indices in per-lane regs;
// __shfl distributes them so all ~13 row gathers per lane are independent and
// in flight together (bandwidth-bound, not latency-bound).
// R3 fix: shfl must execute with ALL lanes active (shfl from an inactive lane
// is undefined and was garbling indices 48/49 of each bag). Clamp the source
// lane and keep the shfl outside the divergent guard.

__global__ __launch_bounds__(256) void FreqAwareEmbedding_kernel(
    const int* __restrict__ indices,    // [T]
    const int* __restrict__ offsets,    // [B]
    const float4* __restrict__ weight4, // [V*16] (V x 64 fp32 as float4)
    float4* __restrict__ out4,          // [B*16]
    int B, int T)
{
    const int wave = (int)((blockIdx.x * blockDim.x + threadIdx.x) >> 6);
    if (wave >= B) return;
    const int lane = threadIdx.x & 63;
    const int sub  = lane >> 4;   // 0..3: index slot within group of 4
    const int col  = lane & 15;   // float4 column within the 64-float row

    const int start = offsets[wave];
    const int end   = (wave + 1 < B) ? offsets[wave + 1] : T;
    const int count = end - start;

    float4 acc = make_float4(0.f, 0.f, 0.f, 0.f);

    if (count <= 64) {
        // Whole bag's indices in one coalesced load, one per lane.
        int myidx = 0;
        if (lane < count) myidx = indices[start + lane];

        #pragma unroll
        for (int t = 0; t < 16; ++t) {
            const int j  = sub + 4 * t;
            const int jj = (j < count) ? j : 0;        // always a valid, active src lane
            const int idx = __shfl(myidx, jj, 64);     // ALL 64 lanes active here
            if (j < count) {
                const float4 v = weight4[(size_t)idx * 16 + col];
                acc.x += v.x; acc.y += v.y; acc.z += v.z; acc.w += v.w;
            }
        }
    } else {
        // Generic fallback (not hit for L=50).
        for (int j = sub; j < count; j += 4) {
            const int idx = indices[start + j];
            const float4 v = weight4[(size_t)idx * 16 + col];
            acc.x += v.x; acc.y += v.y; acc.z += v.z; acc.w += v.w;
        }
    }

    // Reduce the 4 sub-group partials: lanes l, l^16, l^32, l^48 share `col`.
    #pragma unroll
    for (int m = 16; m <= 32; m <<= 1) {
        acc.x += __shfl_xor(acc.x, m, 64);
        acc.y += __shfl_xor(acc.y, m, 64);
        acc.z += __shfl_xor(acc.z, m, 64);
        acc.w += __shfl_xor(acc.w, m, 64);
    }

    const float inv = 1.0f / (float)((count > 0) ? count : 1);
    acc.x *= inv; acc.y *= inv; acc.z *= inv; acc.w *= inv;

    if (sub == 0) {
        out4[(size_t)wave * 16 + col] = acc;
    }
}

extern "C" void kernel_launch(void* const* d_in, const int* in_sizes, int n_in,
                              void* d_out, int out_size, void* d_ws, size_t ws_size,
                              hipStream_t stream) {
    const int*   indices = (const int*)d_in[0];
    const int*   offsets = (const int*)d_in[1];
    const float* weight  = (const float*)d_in[2];

    const int T = in_sizes[0];
    const int B = in_sizes[1];

    const int bags_per_block = 4;   // 256 threads = 4 waves
    const int grid = (B + bags_per_block - 1) / bags_per_block;

    FreqAwareEmbedding_kernel<<<grid, 256, 0, stream>>>(
        indices, offsets, (const float4*)weight, (float4*)d_out, B, T);
}